// Round 3
// baseline (218.483 us; speedup 1.0000x reference)
//
#include <hip/hip_runtime.h>
#include <hip/hip_bf16.h>

// Problem: out[b,o] = sum_i inputs[b,i] * mean[indices[i,o]] + bias[o]
// B=2048, IN=4096, OUT=4096.  inputs f32, indices i32, mean f32, bias f32, out f32.

#define M_DIM 2048
#define K_DIM 4096
#define N_DIM 4096

#define BM 128
#define BN 256
#define BK 32
#define NT (K_DIM / BK)             // 128 K-tiles
#define TILE_A (BM * BK * 2)        // 8192 B
#define TILE_B (BN * BK * 2)        // 16384 B
#define TILE   (TILE_A + TILE_B)    // 24576 B

typedef __attribute__((ext_vector_type(8))) short short8v;
typedef __attribute__((ext_vector_type(4))) float f32x4;

__device__ __forceinline__ unsigned short f2bf(float x) {
    unsigned u = __builtin_bit_cast(unsigned, x);
    u += 0x7fffu + ((u >> 16) & 1u);   // round-to-nearest-even
    return (unsigned short)(u >> 16);
}

__device__ __forceinline__ void gload_lds16(const void* g, void* l) {
    __builtin_amdgcn_global_load_lds(
        (const __attribute__((address_space(1))) void*)(uintptr_t)g,
        (__attribute__((address_space(3))) void*)(uintptr_t)l, 16, 0, 0);
}

// ---------------- Kernel 1: A f32 -> bf16 ----------------
__global__ void convert_a_kernel(const float* __restrict__ A,
                                 unsigned short* __restrict__ Abf) {
    int i = blockIdx.x * blockDim.x + threadIdx.x;
    const float4 v = ((const float4*)A)[i];
    ushort4 o;
    o.x = f2bf(v.x); o.y = f2bf(v.y); o.z = f2bf(v.z); o.w = f2bf(v.w);
    ((ushort4*)Abf)[i] = o;
}

// ------------- Kernel 2: decode + transpose: Wt[n][k] = bf16(mean[indices[k][n]]) -------------
__global__ void decode_transpose_kernel(const int* __restrict__ idx,
                                        const float* __restrict__ mean,
                                        unsigned short* __restrict__ Wt) {
    __shared__ float smean[K_DIM];
    __shared__ unsigned short tile[64][65];
    const int t = threadIdx.x;
    for (int i = t; i < K_DIM; i += 256) smean[i] = mean[i];
    __syncthreads();

    const int k0 = blockIdx.y * 64;
    const int n0 = blockIdx.x * 64;
    const int rb = t >> 4;
    const int cb = (t & 15) * 4;

    #pragma unroll
    for (int i = 0; i < 4; ++i) {
        const int r = rb + i * 16;
        const int4 v = *(const int4*)&idx[(size_t)(k0 + r) * N_DIM + n0 + cb];
        tile[cb + 0][r] = f2bf(smean[v.x]);
        tile[cb + 1][r] = f2bf(smean[v.y]);
        tile[cb + 2][r] = f2bf(smean[v.z]);
        tile[cb + 3][r] = f2bf(smean[v.w]);
    }
    __syncthreads();

    #pragma unroll
    for (int i = 0; i < 4; ++i) {
        const int r = rb + i * 16;
        ushort4 o;
        o.x = tile[r][cb + 0];
        o.y = tile[r][cb + 1];
        o.z = tile[r][cb + 2];
        o.w = tile[r][cb + 3];
        *(ushort4*)&Wt[(size_t)(n0 + r) * K_DIM + k0 + cb] = o;
    }
}

// ---------------- Kernel 3: bf16 GEMM  C = Abf @ Wt^T + bias ----------------
// 4 waves (1M x 4N), per-wave 128x64 (8x4 16x16x32 frags), BK=32.
// Quad-buffered LDS (4 x 24 KiB). Depth-1 register pipeline per K-tile:
//   vmcnt(6) -> barrier -> 12 ds_reads (tile t+1, ping-pong frag sets)
//   -> 6 global_load_lds (tile t+3) -> sched_barrier -> 32 MFMA (tile t).
// Counted vmcnt never drains to 0 in the main loop (T4).
// Swizzle (BK=32, 4 chunks/row, row stride 64B): chunk c stored at LDS chunk
// c' = (c + (row>>1)) & 3, applied on the pre-swizzled GLOBAL source (linear
// LDS dest), undone on ds_read => 2-way bank aliasing only (free).

#define VM6  asm volatile("s_waitcnt vmcnt(6)" ::: "memory")
#define VM0  asm volatile("s_waitcnt vmcnt(0)" ::: "memory")
#define VM12 asm volatile("s_waitcnt vmcnt(12)" ::: "memory")

#define STAGE(buf, t) do {                          \
    const int ko_ = (t) * BK;                       \
    gload_lds16(sA0 + ko_, (buf) + lA0);            \
    gload_lds16(sA1 + ko_, (buf) + lA1);            \
    gload_lds16(sB0 + ko_, (buf) + lB0);            \
    gload_lds16(sB1 + ko_, (buf) + lB1);            \
    gload_lds16(sB2 + ko_, (buf) + lB2);            \
    gload_lds16(sB3 + ko_, (buf) + lB3);            \
} while (0)

#define READ(aS, bS, buf) do {                      \
    aS[0] = *(const short8v*)((buf) + rA0);         \
    aS[1] = *(const short8v*)((buf) + rA1);         \
    aS[2] = *(const short8v*)((buf) + rA2);         \
    aS[3] = *(const short8v*)((buf) + rA3);         \
    aS[4] = *(const short8v*)((buf) + rA4);         \
    aS[5] = *(const short8v*)((buf) + rA5);         \
    aS[6] = *(const short8v*)((buf) + rA6);         \
    aS[7] = *(const short8v*)((buf) + rA7);         \
    bS[0] = *(const short8v*)((buf) + rB0);         \
    bS[1] = *(const short8v*)((buf) + rB1);         \
    bS[2] = *(const short8v*)((buf) + rB2);         \
    bS[3] = *(const short8v*)((buf) + rB3);         \
} while (0)

#define MM1(aS, bS, i, j) \
    acc[i][j] = __builtin_amdgcn_mfma_f32_16x16x32_bf16(aS[i], bS[j], acc[i][j], 0, 0, 0)

#define MM(aS, bS) do {                                              \
    MM1(aS,bS,0,0); MM1(aS,bS,0,1); MM1(aS,bS,0,2); MM1(aS,bS,0,3);  \
    MM1(aS,bS,1,0); MM1(aS,bS,1,1); MM1(aS,bS,1,2); MM1(aS,bS,1,3);  \
    MM1(aS,bS,2,0); MM1(aS,bS,2,1); MM1(aS,bS,2,2); MM1(aS,bS,2,3);  \
    MM1(aS,bS,3,0); MM1(aS,bS,3,1); MM1(aS,bS,3,2); MM1(aS,bS,3,3);  \
    MM1(aS,bS,4,0); MM1(aS,bS,4,1); MM1(aS,bS,4,2); MM1(aS,bS,4,3);  \
    MM1(aS,bS,5,0); MM1(aS,bS,5,1); MM1(aS,bS,5,2); MM1(aS,bS,5,3);  \
    MM1(aS,bS,6,0); MM1(aS,bS,6,1); MM1(aS,bS,6,2); MM1(aS,bS,6,3);  \
    MM1(aS,bS,7,0); MM1(aS,bS,7,1); MM1(aS,bS,7,2); MM1(aS,bS,7,3);  \
} while (0)

// Full pipelined iteration: compute tile t (cur frags), read tile t+1 (nxt),
// stage tile t+3 into stbuf.
#define ITER_FULL(t, cA, cB, nA, nB, rdbuf, stbuf) do {  \
    VM6;                                                 \
    __builtin_amdgcn_s_barrier();                        \
    READ(nA, nB, rdbuf);                                 \
    STAGE(stbuf, (t) + 3);                               \
    __builtin_amdgcn_sched_barrier(0);                   \
    __builtin_amdgcn_s_setprio(1);                       \
    MM(cA, cB);                                          \
    __builtin_amdgcn_s_setprio(0);                       \
} while (0)

__global__ __launch_bounds__(256, 1) void gemm_kernel(
        const unsigned short* __restrict__ Abf,   // [M][K]
        const unsigned short* __restrict__ Wt,    // [N][K]
        const float* __restrict__ bias,           // [N]
        float* __restrict__ C) {                  // [M][N]
    __shared__ __align__(128) char lds[4 * TILE];   // 96 KiB

    const int tid  = threadIdx.x;                 // 0..255
    const int lane = tid & 63;
    const int wn   = tid >> 6;                    // wave 0..3 = N-quadrant
    const int lr   = lane & 15;
    const int kq   = lane >> 4;                   // 0..3

    // XCD-chunked bijective block swizzle (256 blocks, 8 XCDs, 32/XCD)
    const int bid = blockIdx.x;
    const int wg  = (bid & 7) * 32 + (bid >> 3);
    const int m0  = (wg >> 4) * BM;               // 16 M-blocks
    const int n0  = (wg & 15) * BN;               // 16 N-blocks

    // ---- staging: slot p (16B): row = p>>2, lds chunk c' = p&3,
    //      global chunk cg = (c' - (row>>1)) & 3  (row>>1 == p>>3)
    const int pA0 = tid,        pA1 = 256 + tid;             // 512 A slots
    const int pB0 = tid,        pB1 = 256 + tid;             // 1024 B slots
    const int pB2 = 512 + tid,  pB3 = 768 + tid;
#define SRCA(p) (Abf + (size_t)(m0 + ((p) >> 2)) * K_DIM + 8 * ((((p) & 3) - (((p) >> 3) & 3)) & 3))
#define SRCB(p) (Wt  + (size_t)(n0 + ((p) >> 2)) * K_DIM + 8 * ((((p) & 3) - (((p) >> 3) & 3)) & 3))
    const unsigned short* sA0 = SRCA(pA0);
    const unsigned short* sA1 = SRCA(pA1);
    const unsigned short* sB0 = SRCB(pB0);
    const unsigned short* sB1 = SRCB(pB1);
    const unsigned short* sB2 = SRCB(pB2);
    const unsigned short* sB3 = SRCB(pB3);
    const int lA0 = pA0 * 16,          lA1 = pA1 * 16;
    const int lB0 = TILE_A + pB0 * 16, lB1 = TILE_A + pB1 * 16;
    const int lB2 = TILE_A + pB2 * 16, lB3 = TILE_A + pB3 * 16;

    // ---- fragment read byte offsets (swizzled chunk folded in; lane-const)
    const int sc  = ((kq + (lr >> 1)) & 3) * 16;
    const int rA0 = ( 0 * 16 + lr) * 64 + sc;
    const int rA1 = ( 1 * 16 + lr) * 64 + sc;
    const int rA2 = ( 2 * 16 + lr) * 64 + sc;
    const int rA3 = ( 3 * 16 + lr) * 64 + sc;
    const int rA4 = ( 4 * 16 + lr) * 64 + sc;
    const int rA5 = ( 5 * 16 + lr) * 64 + sc;
    const int rA6 = ( 6 * 16 + lr) * 64 + sc;
    const int rA7 = ( 7 * 16 + lr) * 64 + sc;
    const int rB0 = TILE_A + (wn * 64 +  0 + lr) * 64 + sc;
    const int rB1 = TILE_A + (wn * 64 + 16 + lr) * 64 + sc;
    const int rB2 = TILE_A + (wn * 64 + 32 + lr) * 64 + sc;
    const int rB3 = TILE_A + (wn * 64 + 48 + lr) * 64 + sc;

    char* b0v = (char*)lds;
    char* b1v = (char*)lds + TILE;
    char* b2v = (char*)lds + 2 * TILE;
    char* b3v = (char*)lds + 3 * TILE;

    f32x4 acc[8][4] = {};
    short8v aE[8], bE[4], aO[8], bO[4];

    // ---- prologue: stage tiles 0,1,2; wait tile 0; read its frags ----
    STAGE(b0v, 0);
    STAGE(b1v, 1);
    STAGE(b2v, 2);
    VM12;                                   // tile 0 landed (1,2 in flight)
    __builtin_amdgcn_s_barrier();
    READ(aE, bE, b0v);

    // ---- main loop: t = 0 .. 123 (stages up to tile 126) ----
    for (int tt = 0; tt < 31; ++tt) {
        const int t = tt * 4;
        ITER_FULL(t + 0, aE, bE, aO, bO, b1v, b3v);
        ITER_FULL(t + 1, aO, bO, aE, bE, b2v, b0v);
        ITER_FULL(t + 2, aE, bE, aO, bO, b3v, b1v);
        ITER_FULL(t + 3, aO, bO, aE, bE, b0v, b2v);
    }
    // t = 124: full iteration, stages tile 127 (last)
    ITER_FULL(124, aE, bE, aO, bO, b1v, b3v);
    // t = 125: no stage; wait tile 126 (in flight: 126,127 -> vmcnt(6))
    VM6;
    __builtin_amdgcn_s_barrier();
    READ(aE, bE, b2v);
    __builtin_amdgcn_sched_barrier(0);
    MM(aO, bO);
    // t = 126: no stage; wait tile 127 (vmcnt(0))
    VM0;
    __builtin_amdgcn_s_barrier();
    READ(aO, bO, b3v);
    __builtin_amdgcn_sched_barrier(0);
    MM(aE, bE);
    // t = 127
    MM(aO, bO);

    // ---- epilogue: C[m][n] = acc + bias[n] ----
    #pragma unroll
    for (int j = 0; j < 4; ++j) {
        const int n = n0 + wn * 64 + j * 16 + lr;
        const float bv = bias[n];
        #pragma unroll
        for (int i = 0; i < 8; ++i) {
            const int mb = m0 + i * 16 + kq * 4;
            #pragma unroll
            for (int q = 0; q < 4; ++q)
                C[(size_t)(mb + q) * N_DIM + n] = acc[i][j][q] + bv;
        }
    }
}

extern "C" void kernel_launch(void* const* d_in, const int* in_sizes, int n_in,
                              void* d_out, int out_size, void* d_ws, size_t ws_size,
                              hipStream_t stream) {
    const float* inputs  = (const float*)d_in[0];   // (2048, 4096) f32
    const int*   indices = (const int*)  d_in[1];   // (4096, 4096) i32
    const float* mean    = (const float*)d_in[2];   // (4096,) f32
    const float* bias    = (const float*)d_in[3];   // (4096,) f32
    float* out = (float*)d_out;                     // (2048, 4096) f32

    unsigned short* Abf = (unsigned short*)d_ws;                                      // 16 MiB
    unsigned short* Wt  = (unsigned short*)((char*)d_ws + (size_t)M_DIM * K_DIM * 2); // 32 MiB

    convert_a_kernel<<<(M_DIM * K_DIM / 4) / 256, 256, 0, stream>>>(inputs, Abf);
    decode_transpose_kernel<<<dim3(N_DIM / 64, K_DIM / 64), 256, 0, stream>>>(indices, mean, Wt);
    gemm_kernel<<<256, 256, 0, stream>>>(Abf, Wt, bias, out);
}

// Round 6
// 203.069 us; speedup vs baseline: 1.0759x; 1.0759x over previous
//
#include <hip/hip_runtime.h>
#include <hip/hip_bf16.h>

// Problem: out[b,o] = sum_i inputs[b,i] * mean[indices[i,o]] + bias[o]
// B=2048, IN=4096, OUT=4096.  inputs f32, indices i32, mean f32, bias f32, out f32.

#define M_DIM 2048
#define K_DIM 4096
#define N_DIM 4096

#define BM 128
#define BN 256
#define BK 64
#define NT (K_DIM / BK)                       // 64 K-tiles
#define LDSA_BYTES (BM * BK * 2)              // 16384
#define LDSB_BYTES (BN * BK * 2)              // 32768
#define LDS_TILE   (LDSA_BYTES + LDSB_BYTES)  // 49152

typedef __attribute__((ext_vector_type(8))) short short8v;
typedef __attribute__((ext_vector_type(4))) float f32x4;

__device__ __forceinline__ unsigned short f2bf(float x) {
    unsigned u = __builtin_bit_cast(unsigned, x);
    u += 0x7fffu + ((u >> 16) & 1u);   // round-to-nearest-even
    return (unsigned short)(u >> 16);
}

__device__ __forceinline__ void gload_lds16(const void* g, void* l) {
    __builtin_amdgcn_global_load_lds(
        (const __attribute__((address_space(1))) void*)(uintptr_t)g,
        (__attribute__((address_space(3))) void*)(uintptr_t)l, 16, 0, 0);
}

// ---------------- Kernel 1: A f32 -> bf16 ----------------
__global__ void convert_a_kernel(const float* __restrict__ A,
                                 unsigned short* __restrict__ Abf) {
    int i = blockIdx.x * blockDim.x + threadIdx.x;
    const float4 v = ((const float4*)A)[i];
    ushort4 o;
    o.x = f2bf(v.x); o.y = f2bf(v.y); o.z = f2bf(v.z); o.w = f2bf(v.w);
    ((ushort4*)Abf)[i] = o;
}

// ------------- Kernel 2: decode + transpose: Wt[n][k] = bf16(mean[indices[k][n]]) -------------
__global__ void decode_transpose_kernel(const int* __restrict__ idx,
                                        const float* __restrict__ mean,
                                        unsigned short* __restrict__ Wt) {
    __shared__ float smean[K_DIM];
    __shared__ unsigned short tile[64][65];
    const int t = threadIdx.x;
    for (int i = t; i < K_DIM; i += 256) smean[i] = mean[i];
    __syncthreads();

    const int k0 = blockIdx.y * 64;
    const int n0 = blockIdx.x * 64;
    const int rb = t >> 4;
    const int cb = (t & 15) * 4;

    #pragma unroll
    for (int i = 0; i < 4; ++i) {
        const int r = rb + i * 16;
        const int4 v = *(const int4*)&idx[(size_t)(k0 + r) * N_DIM + n0 + cb];
        tile[cb + 0][r] = f2bf(smean[v.x]);
        tile[cb + 1][r] = f2bf(smean[v.y]);
        tile[cb + 2][r] = f2bf(smean[v.z]);
        tile[cb + 3][r] = f2bf(smean[v.w]);
    }
    __syncthreads();

    #pragma unroll
    for (int i = 0; i < 4; ++i) {
        const int r = rb + i * 16;
        ushort4 o;
        o.x = tile[r][cb + 0];
        o.y = tile[r][cb + 1];
        o.z = tile[r][cb + 2];
        o.w = tile[r][cb + 3];
        *(ushort4*)&Wt[(size_t)(n0 + r) * K_DIM + k0 + cb] = o;
    }
}

// ---------------- Kernel 3: bf16 GEMM  C = Abf @ Wt^T + bias ----------------
// Round-2 geometry (BM=128 x BN=256, BK=64, 8 waves 2Mx4N, per-wave 64x64,
// triple-buffered LDS, prefetch distance 2, counted VM6) with ONE barrier per
// K-tile instead of four:
//   per tile: 16 ds_read_b128 (kk0 E-set + kk1 O-set) + 6 global_load_lds
//             (tile t+2) + setprio(1) + 32 MFMA + setprio(0) + VM6 + barrier.
// Race audit: reads hit cbuf (filled 2 tiles ago; every wave's OWN VM6 before
// the barrier at end of tile t-1 confirmed its stage-loads landed, so after
// that barrier ALL loads of the tile have landed); stages hit sbuf whose last
// readers lgkm-drained before their MFMAs, hence before the barrier at end of
// tile t-1, and the stage is issued after that barrier.
// BUGFIX vs round 4: kk1 swizzled chunk is c0^4, which is +64 bytes when
// c0<4 but -64 when c0>=4 (lanes with lr&4). Use per-thread so1=((c0^4)-c0)*16.

#define VM6  asm volatile("s_waitcnt vmcnt(6)" ::: "memory")
#define VM0  asm volatile("s_waitcnt vmcnt(0)" ::: "memory")

#define STG6(buf, t) do {                           \
    const int ko_ = (t) * BK;                       \
    gload_lds16(sA0 + ko_, (buf) + lA0);            \
    gload_lds16(sA1 + ko_, (buf) + lA1);            \
    gload_lds16(sB0 + ko_, (buf) + lB0);            \
    gload_lds16(sB1 + ko_, (buf) + lB1);            \
    gload_lds16(sB2 + ko_, (buf) + lB2);            \
    gload_lds16(sB3 + ko_, (buf) + lB3);            \
} while (0)

#define READ8(aS, bS, buf, so) do {                 \
    aS[0] = *(const short8v*)((buf) + rA0 + (so));  \
    aS[1] = *(const short8v*)((buf) + rA1 + (so));  \
    aS[2] = *(const short8v*)((buf) + rA2 + (so));  \
    aS[3] = *(const short8v*)((buf) + rA3 + (so));  \
    bS[0] = *(const short8v*)((buf) + rB0 + (so));  \
    bS[1] = *(const short8v*)((buf) + rB1 + (so));  \
    bS[2] = *(const short8v*)((buf) + rB2 + (so));  \
    bS[3] = *(const short8v*)((buf) + rB3 + (so));  \
} while (0)

#define MM1(aS, bS, i, j) \
    acc[i][j] = __builtin_amdgcn_mfma_f32_16x16x32_bf16(aS[i], bS[j], acc[i][j], 0, 0, 0)

#define MM16(aS, bS) do {                                            \
    MM1(aS,bS,0,0); MM1(aS,bS,0,1); MM1(aS,bS,0,2); MM1(aS,bS,0,3);  \
    MM1(aS,bS,1,0); MM1(aS,bS,1,1); MM1(aS,bS,1,2); MM1(aS,bS,1,3);  \
    MM1(aS,bS,2,0); MM1(aS,bS,2,1); MM1(aS,bS,2,2); MM1(aS,bS,2,3);  \
    MM1(aS,bS,3,0); MM1(aS,bS,3,1); MM1(aS,bS,3,2); MM1(aS,bS,3,3);  \
} while (0)

// One K-tile: compute cbuf, stage tile (t+2) into sbuf, then VM6 + barrier.
#define ITER(cbuf, sbuf, tstage) do {               \
    READ8(aE, bE, cbuf, 0);                         \
    READ8(aO, bO, cbuf, so1);                       \
    STG6(sbuf, tstage);                             \
    __builtin_amdgcn_s_setprio(1);                  \
    MM16(aE, bE);                                   \
    MM16(aO, bO);                                   \
    __builtin_amdgcn_s_setprio(0);                  \
    VM6;                                            \
    __builtin_amdgcn_s_barrier();                   \
} while (0)

// Tail tiles: no staging; WAITC = VM0 before last tile's buffer use.
#define ITER_NOSTG(cbuf, WAITC) do {                \
    READ8(aE, bE, cbuf, 0);                         \
    READ8(aO, bO, cbuf, so1);                       \
    __builtin_amdgcn_s_setprio(1);                  \
    MM16(aE, bE);                                   \
    MM16(aO, bO);                                   \
    __builtin_amdgcn_s_setprio(0);                  \
    WAITC;                                          \
    __builtin_amdgcn_s_barrier();                   \
} while (0)

__global__ __launch_bounds__(512, 2) void gemm_kernel(
        const unsigned short* __restrict__ Abf,   // [M][K]
        const unsigned short* __restrict__ Wt,    // [N][K]
        const float* __restrict__ bias,           // [N]
        float* __restrict__ C) {                  // [M][N]
    __shared__ __align__(128) char lds[3 * LDS_TILE];   // 144 KiB

    const int tid  = threadIdx.x;                 // 0..511
    const int lane = tid & 63;
    const int w    = tid >> 6;                    // 0..7
    const int wm   = w >> 2;                      // 0..1
    const int wn   = w & 3;                       // 0..3
    const int lr   = lane & 15;
    const int kq   = lane >> 4;                   // 0..3

    // XCD-chunked bijective block swizzle (256 blocks, 8 XCDs, 32/XCD)
    const int bid = blockIdx.x;
    const int wg  = (bid & 7) * 32 + (bid >> 3);
    const int m0  = (wg >> 4) * BM;               // 16 M-blocks
    const int n0  = (wg & 15) * BN;               // 16 N-blocks

    // ---- staging: slot p (16B): row = p>>3, swz chunk c = (p&7)^(row&7)
    const int pA0 = tid,        pA1 = 512 + tid;
    const int pB0 = tid,        pB1 = 512 + tid;
    const int pB2 = 1024 + tid, pB3 = 1536 + tid;
    const unsigned short* sA0 = Abf + (size_t)(m0 + (pA0 >> 3)) * K_DIM + 8 * ((pA0 & 7) ^ ((pA0 >> 3) & 7));
    const unsigned short* sA1 = Abf + (size_t)(m0 + (pA1 >> 3)) * K_DIM + 8 * ((pA1 & 7) ^ ((pA1 >> 3) & 7));
    const unsigned short* sB0 = Wt  + (size_t)(n0 + (pB0 >> 3)) * K_DIM + 8 * ((pB0 & 7) ^ ((pB0 >> 3) & 7));
    const unsigned short* sB1 = Wt  + (size_t)(n0 + (pB1 >> 3)) * K_DIM + 8 * ((pB1 & 7) ^ ((pB1 >> 3) & 7));
    const unsigned short* sB2 = Wt  + (size_t)(n0 + (pB2 >> 3)) * K_DIM + 8 * ((pB2 & 7) ^ ((pB2 >> 3) & 7));
    const unsigned short* sB3 = Wt  + (size_t)(n0 + (pB3 >> 3)) * K_DIM + 8 * ((pB3 & 7) ^ ((pB3 >> 3) & 7));
    const int lA0 = pA0 * 16,              lA1 = pA1 * 16;
    const int lB0 = LDSA_BYTES + pB0 * 16, lB1 = LDSA_BYTES + pB1 * 16;
    const int lB2 = LDSA_BYTES + pB2 * 16, lB3 = LDSA_BYTES + pB3 * 16;

    // ---- fragment read byte offsets; row&7 == lr&7.
    //      kk0 chunk c0 = kq^(lr&7); kk1 chunk = c0^4 => so1 = ((c0^4)-c0)*16 (= +-64).
    const int c0  = kq ^ (lr & 7);
    const int sc  = c0 * 16;
    const int so1 = ((c0 ^ 4) - c0) * 16;
    const int rA0 = (wm * 64 +  0 + lr) * 128 + sc;
    const int rA1 = (wm * 64 + 16 + lr) * 128 + sc;
    const int rA2 = (wm * 64 + 32 + lr) * 128 + sc;
    const int rA3 = (wm * 64 + 48 + lr) * 128 + sc;
    const int rB0 = LDSA_BYTES + (wn * 64 +  0 + lr) * 128 + sc;
    const int rB1 = LDSA_BYTES + (wn * 64 + 16 + lr) * 128 + sc;
    const int rB2 = LDSA_BYTES + (wn * 64 + 32 + lr) * 128 + sc;
    const int rB3 = LDSA_BYTES + (wn * 64 + 48 + lr) * 128 + sc;

    char* b0v = (char*)lds;
    char* b1v = (char*)lds + LDS_TILE;
    char* b2v = (char*)lds + 2 * LDS_TILE;

    f32x4 acc[4][4] = {};
    short8v aE[4], bE[4], aO[4], bO[4];

    // ---- prologue: stage tiles 0,1; wait tile 0 ----
    STG6(b0v, 0);
    STG6(b1v, 1);
    VM6;                                    // tile 0 landed; tile 1 in flight
    __builtin_amdgcn_s_barrier();

    // ---- main loop: t = 0..59 (stages tiles 2..61); rotation period 3 ----
    for (int tt = 0; tt < 20; ++tt) {
        const int t = tt * 3;
        ITER(b0v, b2v, t + 2);
        ITER(b1v, b0v, t + 3);
        ITER(b2v, b1v, t + 4);
    }
    // t=60: compute b0, stage 62 -> b2;  t=61: compute b1, stage 63 -> b0
    ITER(b0v, b2v, 62);
    ITER(b1v, b0v, 63);
    // t=62: compute b2; VM0 drains tile 63.  t=63: compute b0.
    ITER_NOSTG(b2v, VM0);
    {
        READ8(aE, bE, b0v, 0);
        READ8(aO, bO, b0v, so1);
        __builtin_amdgcn_s_setprio(1);
        MM16(aE, bE);
        MM16(aO, bO);
        __builtin_amdgcn_s_setprio(0);
    }

    // ---- epilogue: C[m][n] = acc + bias[n] ----
    #pragma unroll
    for (int j = 0; j < 4; ++j) {
        const int n = n0 + wn * 64 + j * 16 + lr;
        const float bv = bias[n];
        #pragma unroll
        for (int i = 0; i < 4; ++i) {
            const int mb = m0 + wm * 64 + i * 16 + kq * 4;
            #pragma unroll
            for (int q = 0; q < 4; ++q)
                C[(size_t)(mb + q) * N_DIM + n] = acc[i][j][q] + bv;
        }
    }
}

extern "C" void kernel_launch(void* const* d_in, const int* in_sizes, int n_in,
                              void* d_out, int out_size, void* d_ws, size_t ws_size,
                              hipStream_t stream) {
    const float* inputs  = (const float*)d_in[0];   // (2048, 4096) f32
    const int*   indices = (const int*)  d_in[1];   // (4096, 4096) i32
    const float* mean    = (const float*)d_in[2];   // (4096,) f32
    const float* bias    = (const float*)d_in[3];   // (4096,) f32
    float* out = (float*)d_out;                     // (2048, 4096) f32

    unsigned short* Abf = (unsigned short*)d_ws;                                      // 16 MiB
    unsigned short* Wt  = (unsigned short*)((char*)d_ws + (size_t)M_DIM * K_DIM * 2); // 32 MiB

    convert_a_kernel<<<(M_DIM * K_DIM / 4) / 256, 256, 0, stream>>>(inputs, Abf);
    decode_transpose_kernel<<<dim3(N_DIM / 64, K_DIM / 64), 256, 0, stream>>>(indices, mean, Wt);
    gemm_kernel<<<256, 512, 0, stream>>>(Abf, Wt, bias, out);
}